// Round 1
// baseline (366.051 us; speedup 1.0000x reference)
//
#include <hip/hip_runtime.h>
#include <math.h>

// Problem constants
#define CIN    64
#define OUTC   64
#define BOT    16
#define KK     9          // K*K
#define HH     48
#define WW     48
#define LPIX   (HH*WW)    // 2304
#define WSZ    9216       // BOT*CIN*KK
#define PSZ    1024       // OUTC*BOT
#define PREDCH 10304      // WSZ+PSZ+OUTC
#define GRPSZ  2576       // PREDCH/4
#define BATCH  2

// One block per pixel. 256 threads.
// Phase 1: load 3x3 patch (576 vals) + center (64 vals) to LDS.
// Phase 2: pred = grouped 1x1 conv: 10304 dot-16s -> P[16][576], Q[64][16], dyn_b -> outl.
// Phase 3: per (o,t) pair: one pass over c computes dyn_w element stream,
//          accumulating both nrm2 and patch-dot; out contribution = dot / max(nrm,1e-12).
__global__ __launch_bounds__(256) void dppc_kernel(
    const float* __restrict__ x,     // (B, CIN, H, W)
    const float* __restrict__ Wp,    // (PREDCH, 16)
    const float* __restrict__ bp,    // (PREDCH,)
    float* __restrict__ out)         // (B, OUTC, H, W)
{
    __shared__ float patch[CIN * KK];   // 2304 B
    __shared__ float xc[CIN];           // center values, 256 B
    __shared__ float P[BOT][CIN * KK];  // 36 KB
    __shared__ float Q[OUTC][BOT];      // 4 KB
    __shared__ float outl[OUTC];        // accumulator, seeded with dyn_b

    const int tid = threadIdx.x;
    const int pix = blockIdx.x;
    const int b = pix / LPIX;
    const int l = pix - b * LPIX;
    const int h = l / WW;
    const int w = l - h * WW;

    // ---- Phase 1: patch load (zero-padded 3x3 neighborhood) ----
    const float* xb = x + (size_t)b * CIN * LPIX;
    for (int m = tid; m < CIN * KK; m += 256) {
        const int c = m / KK;
        const int t = m - c * KK;
        const int hi = h + (t / 3) - 1;
        const int wi = w + (t % 3) - 1;
        float v = 0.0f;
        if (hi >= 0 && hi < HH && wi >= 0 && wi < WW)
            v = xb[c * LPIX + hi * WW + wi];
        patch[m] = v;
        if (t == 4) xc[c] = v;   // center
    }
    __syncthreads();

    // ---- Phase 2: pred (grouped 1x1 conv over the 4 channel-groups) ----
    for (int ch = tid; ch < PREDCH; ch += 256) {
        const int g = ch / GRPSZ;          // group index 0..3
        const int cb = g * 16;
        const float4* wr = (const float4*)(Wp + (size_t)ch * 16);
        const float4 w0 = wr[0], w1 = wr[1], w2 = wr[2], w3 = wr[3];
        const float4 a0 = *(const float4*)&xc[cb + 0];
        const float4 a1 = *(const float4*)&xc[cb + 4];
        const float4 a2 = *(const float4*)&xc[cb + 8];
        const float4 a3 = *(const float4*)&xc[cb + 12];
        float s = bp[ch];
        s += w0.x * a0.x + w0.y * a0.y + w0.z * a0.z + w0.w * a0.w;
        s += w1.x * a1.x + w1.y * a1.y + w1.z * a1.z + w1.w * a1.w;
        s += w2.x * a2.x + w2.y * a2.y + w2.z * a2.z + w2.w * a2.w;
        s += w3.x * a3.x + w3.y * a3.y + w3.z * a3.z + w3.w * a3.w;

        if (ch < WSZ) {
            const int d = ch / 576;
            const int m = ch - d * 576;
            P[d][m] = s;
        } else if (ch < WSZ + PSZ) {
            const int i = ch - WSZ;
            Q[i >> 4][i & 15] = s;
        } else {
            outl[ch - (WSZ + PSZ)] = s;    // dyn_b seeds the output accumulator
        }
    }
    __syncthreads();

    // ---- Phase 3: fused dyn_w + norm + dynamic conv, per (o,t) pair ----
    for (int pr = tid; pr < OUTC * KK; pr += 256) {
        const int o = pr / KK;
        const int t = pr - o * KK;
        float q[16];
        #pragma unroll
        for (int d = 0; d < 16; ++d) q[d] = Q[o][d];

        float nrm2 = 0.0f;
        float dp = 0.0f;
        #pragma unroll 4
        for (int c = 0; c < CIN; ++c) {
            const int m = c * KK + t;
            float dw = 0.0f;
            #pragma unroll
            for (int d = 0; d < 16; ++d) dw += q[d] * P[d][m];
            nrm2 += dw * dw;
            dp += dw * patch[m];
        }
        const float nrm = fmaxf(sqrtf(nrm2), 1e-12f);
        atomicAdd(&outl[o], dp / nrm);
    }
    __syncthreads();

    // ---- write out ----
    if (tid < OUTC) {
        out[((size_t)b * OUTC + tid) * LPIX + l] = outl[tid];
    }
}

extern "C" void kernel_launch(void* const* d_in, const int* in_sizes, int n_in,
                              void* d_out, int out_size, void* d_ws, size_t ws_size,
                              hipStream_t stream) {
    const float* x  = (const float*)d_in[0];
    const float* Wp = (const float*)d_in[1];
    const float* bp = (const float*)d_in[2];
    float* out = (float*)d_out;
    (void)in_sizes; (void)n_in; (void)out_size; (void)d_ws; (void)ws_size;

    dim3 grid(BATCH * LPIX);   // 4608 blocks, one per pixel
    dim3 block(256);
    hipLaunchKernelGGL(dppc_kernel, grid, block, 0, stream, x, Wp, bp, out);
}

// Round 2
// 220.238 us; speedup vs baseline: 1.6621x; 1.6621x over previous
//
#include <hip/hip_runtime.h>
#include <math.h>

#define CIN    64
#define OUTC   64
#define BOT    16
#define KK     9
#define HH     48
#define WW     48
#define LPIX   (HH*WW)      // 2304
#define WSZ    9216
#define PSZ    1024
#define PREDCH 10304
#define GRPSZ  2576
#define BATCH  2
#define CPAD   68           // padded c-dim (breaks 32-bank aliasing)

__device__ inline float bf2f(unsigned short u) {
    return __uint_as_float(((unsigned int)u) << 16);
}
__device__ inline unsigned short f2bf(float f) {
    unsigned int u = __float_as_uint(f);
    unsigned int r = (u + 0x7FFFu + ((u >> 16) & 1u)) >> 16;   // RNE
    return (unsigned short)r;
}

// One block = 2 horizontally-adjacent pixels. 576 threads (9 waves).
// Phase 1: 3x3 patches -> LDS as [px][t][c].
// Phase 2: pred (grouped 1x1): P (bf16, [px][d][t][c]), Q ([o][16], stride 17), dyn_b.
// Phase 3 (Gram): G_t = P_t P_t^T (16x16 per t), s_t = P_t patch_t; 4x4 register tiles.
// Phase 4: out[o] = dyn_b[o] + sum_t (q_o . s_t) / max(sqrt(q_o^T G_t q_o), 1e-12).
__global__ __launch_bounds__(576, 5) void dppc2(
    const float* __restrict__ x,
    const float* __restrict__ Wp,
    const float* __restrict__ bp,
    float* __restrict__ out)
{
    __shared__ float          patch[2][KK][CPAD];            //  4.9 KB
    __shared__ unsigned short Pl[2][BOT][KK][CPAD];          // 39.2 KB (bf16)
    __shared__ float          Gm[2][KK][16][16];             // 18.4 KB
    __shared__ float          Sv[2][KK][16];                 //  1.2 KB
    __shared__ float          Qm[2][OUTC * 17];              //  8.7 KB
    __shared__ float          dynb[2][OUTC];                 //  0.5 KB

    const int tid = threadIdx.x;
    const int pix0 = blockIdx.x * 2;
    const int b  = pix0 / LPIX;
    const int l0 = pix0 - b * LPIX;
    const int h  = l0 / WW;
    const int w0 = l0 - h * WW;          // pair is (w0, w0+1), never crosses a row

    // ---- Phase 1: patch loads ----
    const float* xb = x + (size_t)b * CIN * LPIX;
    for (int m = tid; m < 2 * CIN * KK; m += 576) {
        const int px = m / (CIN * KK);
        const int r  = m - px * (CIN * KK);
        const int c  = r / KK;
        const int t  = r - c * KK;
        const int hi = h + t / 3 - 1;
        const int wi = w0 + px + (t % 3) - 1;
        float v = 0.0f;
        if (hi >= 0 && hi < HH && wi >= 0 && wi < WW)
            v = xb[c * LPIX + hi * WW + wi];
        patch[px][t][c] = v;
    }
    __syncthreads();

    // ---- Phase 2: pred = grouped 1x1 conv, both pixels per Wp-row load ----
    for (int ch = tid; ch < PREDCH; ch += 576) {
        const int g = ch / GRPSZ;
        const float4* wr = (const float4*)(Wp + (size_t)ch * 16);
        const float4 w0v = wr[0], w1v = wr[1], w2v = wr[2], w3v = wr[3];
        const float* xc0 = &patch[0][4][g * 16];
        const float* xc1 = &patch[1][4][g * 16];
        const float4 a0 = *(const float4*)(xc0 + 0);
        const float4 a1 = *(const float4*)(xc0 + 4);
        const float4 a2 = *(const float4*)(xc0 + 8);
        const float4 a3 = *(const float4*)(xc0 + 12);
        const float4 b0 = *(const float4*)(xc1 + 0);
        const float4 b1 = *(const float4*)(xc1 + 4);
        const float4 b2 = *(const float4*)(xc1 + 8);
        const float4 b3 = *(const float4*)(xc1 + 12);
        const float bias = bp[ch];
        float s0 = bias, s1 = bias;
        s0 += w0v.x*a0.x + w0v.y*a0.y + w0v.z*a0.z + w0v.w*a0.w;
        s0 += w1v.x*a1.x + w1v.y*a1.y + w1v.z*a1.z + w1v.w*a1.w;
        s0 += w2v.x*a2.x + w2v.y*a2.y + w2v.z*a2.z + w2v.w*a2.w;
        s0 += w3v.x*a3.x + w3v.y*a3.y + w3v.z*a3.z + w3v.w*a3.w;
        s1 += w0v.x*b0.x + w0v.y*b0.y + w0v.z*b0.z + w0v.w*b0.w;
        s1 += w1v.x*b1.x + w1v.y*b1.y + w1v.z*b1.z + w1v.w*b1.w;
        s1 += w2v.x*b2.x + w2v.y*b2.y + w2v.z*b2.z + w2v.w*b2.w;
        s1 += w3v.x*b3.x + w3v.y*b3.y + w3v.z*b3.z + w3v.w*b3.w;

        if (ch < WSZ) {
            const int d = ch / 576;
            const int r = ch - d * 576;
            const int c = r / 9;
            const int t = r - c * 9;
            Pl[0][d][t][c] = f2bf(s0);
            Pl[1][d][t][c] = f2bf(s1);
        } else if (ch < WSZ + PSZ) {
            const int i = ch - WSZ;
            const int o = i >> 4;
            const int j = i & 15;
            Qm[0][o * 17 + j] = s0;
            Qm[1][o * 17 + j] = s1;
        } else {
            const int o = ch - WSZ - PSZ;
            dynb[0][o] = s0;
            dynb[1][o] = s1;
        }
    }
    __syncthreads();

    // ---- Phase 3: Gram matrices G_t (full 16x16, 4x4 reg tiles) + s_t ----
    if (tid < 288) {
        const int px = tid / 144;
        const int r  = tid - px * 144;
        const int t  = r / 16;
        const int q4 = r - t * 16;
        const int ib = q4 >> 2;
        const int jb = q4 & 3;

        const ushort4* Ar[4];
        const ushort4* Br[4];
        #pragma unroll
        for (int a = 0; a < 4; ++a) {
            Ar[a] = (const ushort4*)&Pl[px][4 * ib + a][t][0];
            Br[a] = (const ushort4*)&Pl[px][4 * jb + a][t][0];
        }
        const float4* prow = (const float4*)&patch[px][t][0];

        float acc[4][4] = {};
        float sacc[4]   = {0.f, 0.f, 0.f, 0.f};
        for (int cc = 0; cc < 16; ++cc) {
            float A[4][4], B[4][4];
            #pragma unroll
            for (int a = 0; a < 4; ++a) {
                const ushort4 u = Ar[a][cc];
                A[a][0] = bf2f(u.x); A[a][1] = bf2f(u.y);
                A[a][2] = bf2f(u.z); A[a][3] = bf2f(u.w);
            }
            #pragma unroll
            for (int a = 0; a < 4; ++a) {
                const ushort4 u = Br[a][cc];
                B[a][0] = bf2f(u.x); B[a][1] = bf2f(u.y);
                B[a][2] = bf2f(u.z); B[a][3] = bf2f(u.w);
            }
            #pragma unroll
            for (int a = 0; a < 4; ++a)
                #pragma unroll
                for (int bb = 0; bb < 4; ++bb)
                    #pragma unroll
                    for (int k = 0; k < 4; ++k)
                        acc[a][bb] += A[a][k] * B[bb][k];
            if (jb == 0) {
                const float4 p = prow[cc];
                #pragma unroll
                for (int a = 0; a < 4; ++a)
                    sacc[a] += A[a][0]*p.x + A[a][1]*p.y + A[a][2]*p.z + A[a][3]*p.w;
            }
        }
        #pragma unroll
        for (int a = 0; a < 4; ++a) {
            *(float4*)&Gm[px][t][4 * ib + a][4 * jb] =
                make_float4(acc[a][0], acc[a][1], acc[a][2], acc[a][3]);
        }
        if (jb == 0) {
            #pragma unroll
            for (int a = 0; a < 4; ++a) Sv[px][t][4 * ib + a] = sacc[a];
        }
    }
    __syncthreads();

    // ---- Phase 4: out[o] = dyn_b + sum_t (q.s_t)/max(||.||,eps) ----
    if (tid < 128) {
        const int px = tid >> 6;
        const int o  = tid & 63;
        float q[16];
        #pragma unroll
        for (int j = 0; j < 16; ++j) q[j] = Qm[px][o * 17 + j];
        float acc = dynb[px][o];
        for (int t = 0; t < KK; ++t) {
            float nrm2 = 0.0f;
            #pragma unroll
            for (int i = 0; i < 16; ++i) {
                const float4* gr = (const float4*)&Gm[px][t][i][0];
                const float4 g0 = gr[0], g1 = gr[1], g2 = gr[2], g3 = gr[3];
                float u = g0.x*q[0] + g0.y*q[1] + g0.z*q[2] + g0.w*q[3]
                        + g1.x*q[4] + g1.y*q[5] + g1.z*q[6] + g1.w*q[7]
                        + g2.x*q[8] + g2.y*q[9] + g2.z*q[10] + g2.w*q[11]
                        + g3.x*q[12] + g3.y*q[13] + g3.z*q[14] + g3.w*q[15];
                nrm2 += u * q[i];
            }
            const float4 s0v = *(const float4*)&Sv[px][t][0];
            const float4 s1v = *(const float4*)&Sv[px][t][4];
            const float4 s2v = *(const float4*)&Sv[px][t][8];
            const float4 s3v = *(const float4*)&Sv[px][t][12];
            const float dp = s0v.x*q[0] + s0v.y*q[1] + s0v.z*q[2] + s0v.w*q[3]
                           + s1v.x*q[4] + s1v.y*q[5] + s1v.z*q[6] + s1v.w*q[7]
                           + s2v.x*q[8] + s2v.y*q[9] + s2v.z*q[10] + s2v.w*q[11]
                           + s3v.x*q[12] + s3v.y*q[13] + s3v.z*q[14] + s3v.w*q[15];
            nrm2 = fmaxf(nrm2, 0.0f);
            const float nrm = fmaxf(sqrtf(nrm2), 1e-12f);
            acc += dp / nrm;
        }
        out[((size_t)b * OUTC + o) * LPIX + l0 + px] = acc;
    }
}

extern "C" void kernel_launch(void* const* d_in, const int* in_sizes, int n_in,
                              void* d_out, int out_size, void* d_ws, size_t ws_size,
                              hipStream_t stream) {
    const float* x  = (const float*)d_in[0];
    const float* Wp = (const float*)d_in[1];
    const float* bp = (const float*)d_in[2];
    float* out = (float*)d_out;
    (void)in_sizes; (void)n_in; (void)out_size; (void)d_ws; (void)ws_size;

    dim3 grid(BATCH * LPIX / 2);    // 2304 blocks, 2 pixels each
    dim3 block(576);
    hipLaunchKernelGGL(dppc2, grid, block, 0, stream, x, Wp, bp, out);
}

// Round 3
// 203.403 us; speedup vs baseline: 1.7996x; 1.0828x over previous
//
#include <hip/hip_runtime.h>
#include <math.h>

#define CIN    64
#define OUTC   64
#define BOT    16
#define KK     9
#define HH     48
#define WW     48
#define LPIX   (HH*WW)      // 2304
#define WSZ    9216
#define PSZ    1024
#define PREDCH 10304
#define GRPSZ  2576
#define BATCH  2
#define CPAD   68           // Pl/patch inner pad: 136B rows (8B-aligned, conflict-free)

__device__ inline float bf2f(unsigned short u) {
    return __uint_as_float(((unsigned int)u) << 16);
}
__device__ inline unsigned short f2bf(float f) {
    unsigned int u = __float_as_uint(f);
    return (unsigned short)((u + 0x7FFFu + ((u >> 16) & 1u)) >> 16);   // RNE
}
__device__ inline float bfl(unsigned int u) { return __uint_as_float(u << 16); }
__device__ inline float bfh(unsigned int u) { return __uint_as_float(u & 0xFFFF0000u); }

// Pre-kernel: Wp fp32 -> bf16 in workspace (halves phase-2 L2 traffic).
__global__ __launch_bounds__(256) void cvt_wp(const float* __restrict__ Wp,
                                              unsigned short* __restrict__ Wb) {
    const int n = PREDCH * 16;
    for (int i = blockIdx.x * 256 + threadIdx.x; i < n; i += gridDim.x * 256)
        Wb[i] = f2bf(Wp[i]);
}

// One block = 2 adjacent pixels, 576 threads, LDS 62.7 KiB -> 2 blocks/CU.
// Phase 2: pred (bf16 Wp). Phase 3: packed-symmetric Gram (136/t) + s_t.
// Phase 4: 512 threads, out[o] = dyn_b + sum_t (q.s_t)/sqrt(q^T G_t q).
__global__ __launch_bounds__(576, 5) void dppc3(
    const float* __restrict__ x,
    const unsigned short* __restrict__ Wb,
    const float* __restrict__ bp,
    float* __restrict__ out)
{
    __shared__ float          patch[2][KK][CPAD];      //  4896 B
    __shared__ unsigned short Pl[2][BOT][KK][CPAD];    // 39168 B (bf16)
    __shared__ float          Gp[2 * KK * 136];        //  9792 B (packed upper-tri)
    __shared__ float          Sv[2][KK][16];           //  1152 B
    __shared__ float          Qm[2][OUTC * 17];        //  8704 B
    __shared__ float          dynb[2][OUTC];           //   512 B

    const int tid = threadIdx.x;
    const int pix0 = blockIdx.x * 2;
    const int b  = pix0 / LPIX;
    const int l0 = pix0 - b * LPIX;
    const int h  = l0 / WW;
    const int w0 = l0 - h * WW;

    // ---- Phase 1: 3x3 patches -> LDS [px][t][c] ----
    const float* xb = x + (size_t)b * CIN * LPIX;
    for (int m = tid; m < 2 * CIN * KK; m += 576) {
        const int px = m / (CIN * KK);
        const int r  = m - px * (CIN * KK);
        const int c  = r / KK;
        const int t  = r - c * KK;
        const int hi = h + t / 3 - 1;
        const int wi = w0 + px + (t % 3) - 1;
        float v = 0.0f;
        if (hi >= 0 && hi < HH && wi >= 0 && wi < WW)
            v = xb[c * LPIX + hi * WW + wi];
        patch[px][t][c] = v;
    }
    __syncthreads();

    // ---- Phase 2: pred = grouped 1x1 conv (bf16 Wp rows, both pixels) ----
    for (int ch = tid; ch < PREDCH; ch += 576) {
        const int g = ch / GRPSZ;
        const uint4* wr = (const uint4*)(Wb + (size_t)ch * 16);
        const uint4 ua = wr[0], ub = wr[1];
        float wv[16];
        wv[0]=bfl(ua.x);  wv[1]=bfh(ua.x);  wv[2]=bfl(ua.y);  wv[3]=bfh(ua.y);
        wv[4]=bfl(ua.z);  wv[5]=bfh(ua.z);  wv[6]=bfl(ua.w);  wv[7]=bfh(ua.w);
        wv[8]=bfl(ub.x);  wv[9]=bfh(ub.x);  wv[10]=bfl(ub.y); wv[11]=bfh(ub.y);
        wv[12]=bfl(ub.z); wv[13]=bfh(ub.z); wv[14]=bfl(ub.w); wv[15]=bfh(ub.w);
        const float* xc0 = &patch[0][4][g * 16];
        const float* xc1 = &patch[1][4][g * 16];
        const float bias = bp[ch];
        float s0 = bias, s1 = bias;
        #pragma unroll
        for (int k = 0; k < 16; ++k) { s0 += wv[k] * xc0[k]; s1 += wv[k] * xc1[k]; }

        if (ch < WSZ) {
            const int d = ch / 576;
            const int r = ch - d * 576;
            const int c = r / 9;
            const int t = r - c * 9;
            Pl[0][d][t][c] = f2bf(s0);
            Pl[1][d][t][c] = f2bf(s1);
        } else if (ch < WSZ + PSZ) {
            const int i = ch - WSZ;
            Qm[0][(i >> 4) * 17 + (i & 15)] = s0;
            Qm[1][(i >> 4) * 17 + (i & 15)] = s1;
        } else {
            dynb[0][ch - WSZ - PSZ] = s0;
            dynb[1][ch - WSZ - PSZ] = s1;
        }
    }
    __syncthreads();

    // ---- Phase 3: Gram (packed upper-tri) + s_t; 288 threads, 4x4 reg tiles ----
    if (tid < 288) {
        const int px = tid / 144;
        const int r  = tid - px * 144;
        const int t  = r / 16;
        const int q4 = r - t * 16;
        const int ib = q4 >> 2;
        const int jb = q4 & 3;

        const ushort4* Ar[4];
        const ushort4* Br[4];
        #pragma unroll
        for (int a = 0; a < 4; ++a) {
            Ar[a] = (const ushort4*)&Pl[px][4 * ib + a][t][0];
            Br[a] = (const ushort4*)&Pl[px][4 * jb + a][t][0];
        }
        const float4* prow = (const float4*)&patch[px][t][0];

        float acc[4][4] = {};
        float sacc[4]   = {0.f, 0.f, 0.f, 0.f};
        for (int cc = 0; cc < 16; ++cc) {
            float A[4][4], B[4][4];
            #pragma unroll
            for (int a = 0; a < 4; ++a) {
                const ushort4 u = Ar[a][cc];
                A[a][0] = bf2f(u.x); A[a][1] = bf2f(u.y);
                A[a][2] = bf2f(u.z); A[a][3] = bf2f(u.w);
            }
            #pragma unroll
            for (int a = 0; a < 4; ++a) {
                const ushort4 u = Br[a][cc];
                B[a][0] = bf2f(u.x); B[a][1] = bf2f(u.y);
                B[a][2] = bf2f(u.z); B[a][3] = bf2f(u.w);
            }
            #pragma unroll
            for (int a = 0; a < 4; ++a)
                #pragma unroll
                for (int bb = 0; bb < 4; ++bb)
                    #pragma unroll
                    for (int k = 0; k < 4; ++k)
                        acc[a][bb] += A[a][k] * B[bb][k];
            if (jb == 0) {
                const float4 p = prow[cc];
                #pragma unroll
                for (int a = 0; a < 4; ++a)
                    sacc[a] += A[a][0]*p.x + A[a][1]*p.y + A[a][2]*p.z + A[a][3]*p.w;
            }
        }
        if (ib <= jb) {
            float* g = &Gp[(px * KK + t) * 136];
            #pragma unroll
            for (int a = 0; a < 4; ++a) {
                const int i = 4 * ib + a;
                const int base = 15 * i - (i * (i - 1)) / 2;   // off(i,j) = base + j
                #pragma unroll
                for (int bb = 0; bb < 4; ++bb) {
                    const int j = 4 * jb + bb;
                    if (j >= i) g[base + j] = acc[a][bb];
                }
            }
        }
        if (jb == 0) {
            #pragma unroll
            for (int a = 0; a < 4; ++a) Sv[px][t][4 * ib + a] = sacc[a];
        }
    }
    __syncthreads();

    // ---- Phase 4: 512 threads; 4 lanes per (px,o) split over t ----
    if (tid < 512) {
        const int sub  = tid & 3;
        const int pair = tid >> 2;
        const int px   = pair >> 6;
        const int o    = pair & 63;
        float q[16], q2[16];
        #pragma unroll
        for (int j = 0; j < 16; ++j) {
            q[j]  = Qm[px][o * 17 + j];
            q2[j] = 2.0f * q[j];
        }
        float acc = 0.0f;
        #pragma unroll
        for (int k = 0; k < 3; ++k) {
            const int t = sub + 4 * k;
            if (t <= 8) {
                const float* g = &Gp[(px * KK + t) * 136];
                float nrm2 = 0.0f;
                int off = 0;
                #pragma unroll
                for (int i = 0; i < 16; ++i) {
                    float ui = g[off] * q[i];
                    #pragma unroll
                    for (int j = i + 1; j < 16; ++j) ui += g[off + (j - i)] * q2[j];
                    nrm2 += ui * q[i];
                    off += 16 - i;
                }
                const float* s = &Sv[px][t][0];
                float dp = 0.0f;
                #pragma unroll
                for (int j = 0; j < 16; ++j) dp += s[j] * q[j];
                nrm2 = fmaxf(nrm2, 0.0f);
                const float nrm = fmaxf(sqrtf(nrm2), 1e-12f);
                acc += dp / nrm;
            }
        }
        acc += __shfl_xor(acc, 1);
        acc += __shfl_xor(acc, 2);
        if (sub == 0)
            out[((size_t)b * OUTC + o) * LPIX + l0 + px] = dynb[px][o] + acc;
    }
}

extern "C" void kernel_launch(void* const* d_in, const int* in_sizes, int n_in,
                              void* d_out, int out_size, void* d_ws, size_t ws_size,
                              hipStream_t stream) {
    const float* x  = (const float*)d_in[0];
    const float* Wp = (const float*)d_in[1];
    const float* bp = (const float*)d_in[2];
    float* out = (float*)d_out;
    unsigned short* Wb = (unsigned short*)d_ws;   // PREDCH*16 bf16 = 330 KB
    (void)in_sizes; (void)n_in; (void)out_size; (void)ws_size;

    hipLaunchKernelGGL(cvt_wp, dim3((PREDCH * 16 + 255) / 256), dim3(256), 0, stream, Wp, Wb);
    hipLaunchKernelGGL(dppc3, dim3(BATCH * LPIX / 2), dim3(576), 0, stream, x, Wb, bp, out);
}